// Round 14
// baseline (341.893 us; speedup 1.0000x reference)
//
#include <hip/hip_runtime.h>
#include <math.h>

typedef unsigned short u16;
typedef unsigned int u32;
typedef __bf16 bf16x8 __attribute__((ext_vector_type(8)));
typedef __bf16 bf16x4 __attribute__((ext_vector_type(4)));
typedef float f32x4 __attribute__((ext_vector_type(4)));

#define DIM 2048
#define NHEADS 16
#define NKVH 8
#define HD 128
#define RANK 16
#define INNER 5632
#define BB 2
#define SS 2048
#define NROWS (BB*SS)
#define EPS 1e-5f
#define QSC2 0.12751743560829201f   /* log2(e)/sqrt(128): exp2-domain softmax */
#define LOG2E 1.4426950408889634f

__device__ inline float bf2f(u16 u){ u32 x = ((u32)u)<<16; float f; __builtin_memcpy(&f,&x,4); return f; }
__device__ inline u16 f2bf(float f){ u32 u; __builtin_memcpy(&u,&f,4); u32 r = u + 0x7fffu + ((u>>16)&1u); return (u16)(r>>16); }
__device__ inline u32 pack2(float a, float b){ return (u32)f2bf(a) | ((u32)f2bf(b)<<16); }
__device__ inline u16 bfu(float f){ __bf16 b = (__bf16)f; u16 r; __builtin_memcpy(&r,&b,2); return r; }

__device__ inline float blockReduceSum(float v){
  __shared__ float r[4];
  #pragma unroll
  for(int o=1;o<64;o<<=1) v += __shfl_xor(v, o);
  int wv = threadIdx.x>>6;
  __syncthreads();
  if((threadIdx.x&63)==0) r[wv] = v;
  __syncthreads();
  return r[0]+r[1]+r[2]+r[3];
}

__device__ inline f32x4 blockReduceSum4(f32x4 v){
  __shared__ f32x4 r4[4];
  #pragma unroll
  for(int o=1;o<64;o<<=1){
    v.x += __shfl_xor(v.x,o); v.y += __shfl_xor(v.y,o);
    v.z += __shfl_xor(v.z,o); v.w += __shfl_xor(v.w,o);
  }
  int wv = threadIdx.x>>6;
  __syncthreads();
  if((threadIdx.x&63)==0) r4[wv]=v;
  __syncthreads();
  return r4[0]+r4[1]+r4[2]+r4[3];
}

// ---------------- one-time weight prep: castw (bid<48) + FFN pack (bid>=48) ----------------
__global__ __launch_bounds__(256) void k_prep(const float* __restrict__ wqb,
                                              const float* __restrict__ wkb,
                                              const float* __restrict__ wvb,
                                              const float* __restrict__ w2b,
                                              const float* __restrict__ w1b,
                                              const float* __restrict__ w3b,
                                              const float* __restrict__ w2a,
                                              u16* __restrict__ wqP,
                                              u16* __restrict__ wkvP,
                                              u16* __restrict__ w2P,
                                              u16* __restrict__ wpk){
  int bid = blockIdx.x;
  if(bid < 48){
    const float* src; u16* dst; int off;
    if(bid<16){ src=wqb; dst=wqP; off=bid; }
    else if(bid<24){ src=wkb; dst=wkvP; off=bid-16; }
    else if(bid<32){ src=wvb; dst=wkvP+16384; off=bid-24; }
    else { src=w2b; dst=w2P; off=bid-32; }
    int base = off*2048 + threadIdx.x*8;
    float4 a = ((const float4*)src)[base/4];
    float4 c = ((const float4*)src)[base/4+1];
    uint4 st;
    st.x = pack2(a.x,a.y); st.y = pack2(a.z,a.w);
    st.z = pack2(c.x,c.y); st.w = pack2(c.z,c.w);
    *(uint4*)&dst[base] = st;
  } else {
    int j = (bid-48)*256 + threadIdx.x;
    u32 pw[24];
    #pragma unroll
    for(int i=0;i<8;i++) pw[i]    = pack2(w1b[(size_t)(2*i)*INNER+j], w1b[(size_t)(2*i+1)*INNER+j]);
    #pragma unroll
    for(int i=0;i<8;i++) pw[8+i]  = pack2(w3b[(size_t)(2*i)*INNER+j], w3b[(size_t)(2*i+1)*INNER+j]);
    const float4* wp = (const float4*)(w2a + (size_t)j*16);
    #pragma unroll
    for(int q=0;q<4;q++){ float4 t=wp[q];
      pw[16+2*q] = pack2(t.x,t.y); pw[17+2*q] = pack2(t.z,t.w); }
    uint4* dst = (uint4*)(wpk + (size_t)j*48);
    #pragma unroll
    for(int i=0;i<6;i++) dst[i] = make_uint4(pw[4*i],pw[4*i+1],pw[4*i+2],pw[4*i+3]);
  }
}

// ---------------- RMSNorm: f32 in -> bf16 out (row = block) ----------------
__global__ __launch_bounds__(256) void k_rms(const float* __restrict__ x,
                                             const float* __restrict__ w,
                                             u16* __restrict__ out){
  size_t base = (size_t)blockIdx.x*DIM;
  int tid = threadIdx.x;
  float4 v0 = ((const float4*)(x+base))[tid*2];
  float4 v1 = ((const float4*)(x+base))[tid*2+1];
  float ss = v0.x*v0.x+v0.y*v0.y+v0.z*v0.z+v0.w*v0.w
           + v1.x*v1.x+v1.y*v1.y+v1.z*v1.z+v1.w*v1.w;
  ss = blockReduceSum(ss);
  float rstd = rsqrtf(ss*(1.0f/DIM) + EPS);
  float4 w0 = ((const float4*)w)[tid*2];
  float4 w1 = ((const float4*)w)[tid*2+1];
  uint4 st;
  st.x = pack2(v0.x*w0.x*rstd, v0.y*w0.y*rstd);
  st.y = pack2(v0.z*w0.z*rstd, v0.w*w0.w*rstd);
  st.z = pack2(v1.x*w1.x*rstd, v1.y*w1.y*rstd);
  st.w = pack2(v1.z*w1.z*rstd, v1.w*w1.w*rstd);
  *(uint4*)&out[base + tid*8] = st;
}

// ---------------- LoRA-A split-K: 4 rows/thread, K split in 4 chunks -> partials ------------
template<int NMAT>
__global__ __launch_bounds__(256) void k_loraAs(const u16* __restrict__ X,
                                                const float* __restrict__ A0,
                                                const float* __restrict__ A1,
                                                const float* __restrict__ A2,
                                                float* __restrict__ part){
  constexpr int LDO = NMAT*16;
  int bid = blockIdx.x;
  int mat = bid >> 8;
  int rem = bid & 255;
  int kc  = rem & 3;
  int blk = rem >> 2;
  const float* A = (mat==0) ? A0 : ((NMAT>2 && mat==2) ? A2 : A1);
  int tid = threadIdx.x;
  int ks = tid&15, rg = tid>>4;
  int row0 = blk*64 + rg*4;
  float acc[4][16];
  #pragma unroll
  for(int r=0;r<4;r++)
    #pragma unroll
    for(int c=0;c<16;c++) acc[r][c]=0.f;
  const u16* xp = X + (size_t)row0*DIM + kc*512 + ks*32;
  #pragma unroll
  for(int i8=0;i8<4;i8++){
    bf16x8 x0 = *(const bf16x8*)(xp + i8*8);
    bf16x8 x1 = *(const bf16x8*)(xp + DIM + i8*8);
    bf16x8 x2 = *(const bf16x8*)(xp + 2*DIM + i8*8);
    bf16x8 x3 = *(const bf16x8*)(xp + 3*DIM + i8*8);
    #pragma unroll
    for(int e=0;e<8;e++){
      int k = kc*512 + ks*32 + i8*8 + e;
      const float4* a = (const float4*)(A + (size_t)k*16);
      float4 a0=a[0], a1=a[1], a2=a[2], a3=a[3];
      float xs0=(float)x0[e], xs1=(float)x1[e], xs2=(float)x2[e], xs3=(float)x3[e];
      #define FMAROW(r, xs) \
        acc[r][0]=fmaf(xs,a0.x,acc[r][0]); acc[r][1]=fmaf(xs,a0.y,acc[r][1]); \
        acc[r][2]=fmaf(xs,a0.z,acc[r][2]); acc[r][3]=fmaf(xs,a0.w,acc[r][3]); \
        acc[r][4]=fmaf(xs,a1.x,acc[r][4]); acc[r][5]=fmaf(xs,a1.y,acc[r][5]); \
        acc[r][6]=fmaf(xs,a1.z,acc[r][6]); acc[r][7]=fmaf(xs,a1.w,acc[r][7]); \
        acc[r][8]=fmaf(xs,a2.x,acc[r][8]); acc[r][9]=fmaf(xs,a2.y,acc[r][9]); \
        acc[r][10]=fmaf(xs,a2.z,acc[r][10]); acc[r][11]=fmaf(xs,a2.w,acc[r][11]); \
        acc[r][12]=fmaf(xs,a3.x,acc[r][12]); acc[r][13]=fmaf(xs,a3.y,acc[r][13]); \
        acc[r][14]=fmaf(xs,a3.z,acc[r][14]); acc[r][15]=fmaf(xs,a3.w,acc[r][15]);
      FMAROW(0, xs0) FMAROW(1, xs1) FMAROW(2, xs2) FMAROW(3, xs3)
      #undef FMAROW
    }
  }
  #pragma unroll
  for(int o=1;o<16;o<<=1){
    #pragma unroll
    for(int r=0;r<4;r++)
      #pragma unroll
      for(int c=0;c<16;c++) acc[r][c] += __shfl_xor(acc[r][c], o);
  }
  if(ks==0){
    #pragma unroll
    for(int r=0;r<4;r++){
      float4* op = (float4*)(part + ((size_t)kc*NROWS + row0+r)*LDO + mat*16);
      op[0] = make_float4(acc[r][0],acc[r][1],acc[r][2],acc[r][3]);
      op[1] = make_float4(acc[r][4],acc[r][5],acc[r][6],acc[r][7]);
      op[2] = make_float4(acc[r][8],acc[r][9],acc[r][10],acc[r][11]);
      op[3] = make_float4(acc[r][12],acc[r][13],acc[r][14],acc[r][15]);
    }
  }
}

// ---------------- Q path: LoRA-B (bf16) + LayerNorm + RoPE + scale -> bf16 ----------------
// Reads split-K partials inline (sum of 4 chunks, uniform loads; r13-proven pattern).
__global__ __launch_bounds__(256) void k_qb(const float* __restrict__ part,
                                            const u16* __restrict__ wqP,
                                            const float* __restrict__ bq,
                                            const float* __restrict__ nqw,
                                            const float* __restrict__ nqb,
                                            const float* __restrict__ cosT,
                                            const float* __restrict__ sinT,
                                            u16* __restrict__ qout){
  __shared__ u16 wl[16*2048];  // 64 KB bf16 weights
  const size_t PSTR = (size_t)NROWS*48;
  int tid = threadIdx.x;
  #pragma unroll
  for(int ii=0;ii<16;ii++)
    ((uint4*)wl)[tid + 256*ii] = ((const uint4*)wqP)[tid + 256*ii];
  __syncthreads();
  int j0 = tid*8;
  float bqv[8], nwv[8], nbv[8];
  #pragma unroll
  for(int e=0;e<8;e++){ bqv[e]=bq[j0+e]; nwv[e]=nqw[j0+e]; nbv[e]=nqb[j0+e]; }
  int i0 = (j0&127)>>1;
  for(int rp=0;rp<4;rp++){
    int row = blockIdx.x*8 + rp*2;
    float pre[2][8];
    #pragma unroll
    for(int rr=0;rr<2;rr++){
      float xq[16];
      #pragma unroll
      for(int r=0;r<16;r++){
        size_t bx = (size_t)(row+rr)*48 + r;
        xq[r] = part[bx] + part[bx+PSTR] + part[bx+2*PSTR] + part[bx+3*PSTR];
      }
      #pragma unroll
      for(int e=0;e<8;e++) pre[rr][e]=0.f;
      #pragma unroll
      for(int r=0;r<16;r++){
        bf16x8 wv = *(const bf16x8*)&wl[r*2048 + j0];
        #pragma unroll
        for(int e=0;e<8;e++) pre[rr][e] = fmaf(xq[r], (float)wv[e], pre[rr][e]);
      }
      #pragma unroll
      for(int e=0;e<8;e++) pre[rr][e] = pre[rr][e]*0.0625f + bqv[e];
    }
    f32x4 sv = (f32x4){0.f,0.f,0.f,0.f};
    #pragma unroll
    for(int e=0;e<8;e++){
      sv.x += pre[0][e]; sv.y += pre[0][e]*pre[0][e];
      sv.z += pre[1][e]; sv.w += pre[1][e]*pre[1][e];
    }
    f32x4 red = blockReduceSum4(sv);
    #pragma unroll
    for(int rr=0;rr<2;rr++){
      float mu  = (rr?red.z:red.x)*(1.0f/DIM);
      float var = (rr?red.w:red.y)*(1.0f/DIM) - mu*mu;
      float rstd = rsqrtf(var + EPS);
      float qn[8];
      #pragma unroll
      for(int e=0;e<8;e++) qn[e] = (pre[rr][e]-mu)*rstd*nwv[e] + nbv[e];
      int spos = (row+rr) & (SS-1);
      const float* cp = cosT + spos*64;
      const float* sp = sinT + spos*64;
      uint4 st;
      u32 pk[4];
      #pragma unroll
      for(int p=0;p<4;p++){
        float c = cp[i0+p], sn = sp[i0+p];
        float x0 = qn[2*p], x1 = qn[2*p+1];
        pk[p] = pack2((x0*c - x1*sn)*QSC2, (x0*sn + x1*c)*QSC2);
      }
      st.x=pk[0]; st.y=pk[1]; st.z=pk[2]; st.w=pk[3];
      *(uint4*)&qout[(size_t)(row+rr)*2048 + j0] = st;
    }
  }
}

// ---------------- K/V path: LoRA-B (bf16) (+LN+RoPE for K) -> bf16 ----------------
// Reads split-K partials inline (sum of 4 chunks).
__global__ __launch_bounds__(256) void k_kvb(const float* __restrict__ part,
                                             const u16* __restrict__ wkvP,
                                             const float* __restrict__ bk,
                                             const float* __restrict__ nkw,
                                             const float* __restrict__ nkb,
                                             const float* __restrict__ bv,
                                             const float* __restrict__ cosT,
                                             const float* __restrict__ sinT,
                                             u16* __restrict__ kout,
                                             u16* __restrict__ vout){
  __shared__ u16 wl[2*16*1024];  // 64 KB: [0,16K)=wk_b, [16K,32K)=wv_b
  const size_t PSTR = (size_t)NROWS*48;
  int tid = threadIdx.x;
  #pragma unroll
  for(int ii=0;ii<16;ii++)
    ((uint4*)wl)[tid + 256*ii] = ((const uint4*)wkvP)[tid + 256*ii];
  __syncthreads();
  int j0 = tid*4;
  float bkv[4], nwv[4], nbv[4], bvv[4];
  #pragma unroll
  for(int e=0;e<4;e++){ bkv[e]=bk[j0+e]; nwv[e]=nkw[j0+e]; nbv[e]=nkb[j0+e]; bvv[e]=bv[j0+e]; }
  int i0 = (j0&127)>>1;
  for(int rp=0;rp<4;rp++){
    int row = blockIdx.x*8 + rp*2;
    float pk_[2][4], pv_[2][4];
    #pragma unroll
    for(int rr=0;rr<2;rr++){
      float xk[16], xv[16];
      #pragma unroll
      for(int r=0;r<16;r++){
        size_t bx = (size_t)(row+rr)*48 + 16 + r;
        xk[r] = part[bx] + part[bx+PSTR] + part[bx+2*PSTR] + part[bx+3*PSTR];
        size_t bv2 = (size_t)(row+rr)*48 + 32 + r;
        xv[r] = part[bv2] + part[bv2+PSTR] + part[bv2+2*PSTR] + part[bv2+3*PSTR];
      }
      #pragma unroll
      for(int e=0;e<4;e++){ pk_[rr][e]=0.f; pv_[rr][e]=0.f; }
      #pragma unroll
      for(int r=0;r<16;r++){
        bf16x4 wk4 = *(const bf16x4*)&wl[r*1024 + j0];
        bf16x4 wv4 = *(const bf16x4*)&wl[16384 + r*1024 + j0];
        #pragma unroll
        for(int e=0;e<4;e++){ pk_[rr][e]=fmaf(xk[r],(float)wk4[e],pk_[rr][e]); pv_[rr][e]=fmaf(xv[r],(float)wv4[e],pv_[rr][e]); }
      }
      #pragma unroll
      for(int e=0;e<4;e++){ pk_[rr][e]=pk_[rr][e]*0.0625f + bkv[e]; pv_[rr][e]=pv_[rr][e]*0.0625f + bvv[e]; }
    }
    f32x4 sv = (f32x4){0.f,0.f,0.f,0.f};
    #pragma unroll
    for(int e=0;e<4;e++){
      sv.x += pk_[0][e]; sv.y += pk_[0][e]*pk_[0][e];
      sv.z += pk_[1][e]; sv.w += pk_[1][e]*pk_[1][e];
    }
    f32x4 red = blockReduceSum4(sv);
    #pragma unroll
    for(int rr=0;rr<2;rr++){
      float mu  = (rr?red.z:red.x)*(1.0f/1024.0f);
      float var = (rr?red.w:red.y)*(1.0f/1024.0f) - mu*mu;
      float rstd = rsqrtf(var + EPS);
      float kn[4];
      #pragma unroll
      for(int e=0;e<4;e++) kn[e] = (pk_[rr][e]-mu)*rstd*nwv[e] + nbv[e];
      int spos = (row+rr) & (SS-1);
      const float* cp = cosT + spos*64;
      const float* sp = sinT + spos*64;
      uint2 stk;
      { float c=cp[i0],   sn=sp[i0];   stk.x = pack2(kn[0]*c - kn[1]*sn, kn[0]*sn + kn[1]*c); }
      { float c=cp[i0+1], sn=sp[i0+1]; stk.y = pack2(kn[2]*c - kn[3]*sn, kn[2]*sn + kn[3]*c); }
      *(uint2*)&kout[(size_t)(row+rr)*1024 + j0] = stk;
      uint2 stv; stv.x = pack2(pv_[rr][0],pv_[rr][1]); stv.y = pack2(pv_[rr][2],pv_[rr][3]);
      *(uint2*)&vout[(size_t)(row+rr)*1024 + j0] = stv;
    }
  }
}

// ---------------- V transpose: [b][s][kvh][d] -> [b*kvh][d][s] (64x64 tiles) ----------------
__global__ __launch_bounds__(256) void k_vt(const u16* __restrict__ v,
                                            u16* __restrict__ vt){
  __shared__ u16 tl[64*68];
  int bid = blockIdx.x;
  int st = bid & 31;
  int dt = (bid>>5) & 1;
  int bh = bid>>6;          // b*8 + kvh
  int b = bh>>3, kvh = bh&7;
  int tid = threadIdx.x;
  int s0 = st*64, d0 = dt*64;
  {
    int s_l = tid>>2, dg = tid&3;
    const u16* src = v + ((size_t)(b*SS + s0 + s_l)*NKVH + kvh)*HD + d0 + dg*16;
    *(uint4*)&tl[s_l*68 + dg*16]     = *(const uint4*)(src);
    *(uint4*)&tl[s_l*68 + dg*16 + 8] = *(const uint4*)(src + 8);
  }
  __syncthreads();
  {
    int d_l = tid>>2, sg = tid&3;
    u32 pk[8];
    #pragma unroll
    for(int i=0;i<8;i++){
      u16 a = tl[(sg*16 + 2*i)*68 + d_l];
      u16 c = tl[(sg*16 + 2*i+1)*68 + d_l];
      pk[i] = (u32)a | ((u32)c<<16);
    }
    u16* dst = vt + ((size_t)bh*HD + d0 + d_l)*SS + s0 + sg*16;
    ((uint4*)dst)[0] = make_uint4(pk[0],pk[1],pk[2],pk[3]);
    ((uint4*)dst)[1] = make_uint4(pk[4],pk[5],pk[6],pk[7]);
  }
}

// ---------------- Flash attention (16x16 MFMA, 2 m-blocks/wave, static softmax) ------------
// grid 512; block 256 = 4 waves x 32 q-rows. Named-register staging (no lambdas/arrays).
__global__ __launch_bounds__(256,2) void k_attn(const u16* __restrict__ qb,
                                                const u16* __restrict__ kb,
                                                const u16* __restrict__ vt,
                                                const float* __restrict__ resid,
                                                float* __restrict__ out){
  __shared__ u16 Kc[16*520];    // 16640 B
  __shared__ u16 Vc[8*1032];    // 16512 B
  __shared__ u16 Pl[4][32*72];  // 18432 B
  int bid = ((int)blockIdx.x & 7)*64 + ((int)blockIdx.x >> 3);  // XCD swizzle (512%8==0)
  int qt = bid & 15;
  int h  = (bid>>4) & 15;
  int b  = bid>>8;
  int kvh = h>>1;
  int tid = threadIdx.x;
  int w = tid>>6, lane = tid&63;
  int l16 = lane&15, lg = lane>>4;

  bf16x8 qa[2][4];
  #pragma unroll
  for(int m=0;m<2;m++){
    const u16* qp = qb + ((size_t)(b*SS + qt*128 + w*32 + m*16 + l16))*DIM + h*HD + lg*8;
    #pragma unroll
    for(int c=0;c<4;c++) qa[m][c] = *(const bf16x8*)(qp + c*32);
  }
  f32x4 acc[2][8];
  #pragma unroll
  for(int m=0;m<2;m++)
    #pragma unroll
    for(int n=0;n<8;n++) acc[m][n] = (f32x4){0.f,0.f,0.f,0.f};
  f32x4 lacc0 = (f32x4){0.f,0.f,0.f,0.f};
  f32x4 lacc1 = (f32x4){0.f,0.f,0.f,0.f};
  bf16x8 ones;
  #pragma unroll
  for(int e=0;e<8;e++) ones[e] = (__bf16)1.0f;

  u16* Pw = Pl[w];
  const u16* vtb = vt + (size_t)(b*NKVH + kvh)*HD*SS;
  const u16* kbb = kb + ((size_t)(b*SS)*NKVH + kvh)*HD;
  int k_key = tid>>4, k_dg = tid&15;
  int v_d   = tid>>3, v_kc = tid&7;
  uint4 kA,kB,kC,kD,vA,vB,vC,vD;       // named staging regs (no arrays!)

#define LOAD_STAGE(KT) do{ \
    const u16* ksrc_ = kbb + (size_t)(KT)*64*1024; \
    const u16* vsrc_ = vtb + (KT)*64; \
    kA = *(const uint4*)(ksrc_ + (size_t)(k_key     )*1024 + k_dg*8); \
    kB = *(const uint4*)(ksrc_ + (size_t)(k_key + 16)*1024 + k_dg*8); \
    kC = *(const uint4*)(ksrc_ + (size_t)(k_key + 32)*1024 + k_dg*8); \
    kD = *(const uint4*)(ksrc_ + (size_t)(k_key + 48)*1024 + k_dg*8); \
    vA = *(const uint4*)(vsrc_ + (size_t)(v_d      )*SS + v_kc*8); \
    vB = *(const uint4*)(vsrc_ + (size_t)(v_d + 32 )*SS + v_kc*8); \
    vC = *(const uint4*)(vsrc_ + (size_t)(v_d + 64 )*SS + v_kc*8); \
    vD = *(const uint4*)(vsrc_ + (size_t)(v_d + 96 )*SS + v_kc*8); \
  }while(0)
#define STORE_STAGE() do{ \
    *(uint4*)&Kc[k_dg*520 + (k_key     )*8] = kA; \
    *(uint4*)&Kc[k_dg*520 + (k_key + 16)*8] = kB; \
    *(uint4*)&Kc[k_dg*520 + (k_key + 32)*8] = kC; \
    *(uint4*)&Kc[k_dg*520 + (k_key + 48)*8] = kD; \
    *(uint4*)&Vc[v_kc*1032 + (v_d      )*8] = vA; \
    *(uint4*)&Vc[v_kc*1032 + (v_d + 32 )*8] = vB; \
    *(uint4*)&Vc[v_kc*1032 + (v_d + 64 )*8] = vC; \
    *(uint4*)&Vc[v_kc*1032 + (v_d + 96 )*8] = vD; \
  }while(0)

  LOAD_STAGE(0);
  STORE_STAGE();
  __syncthreads();

  for(int kt=0; kt<SS/64; kt++){
    bool more = (kt+1) < SS/64;
    if(more) LOAD_STAGE(kt+1);    // in flight during compute (T14)
    #pragma unroll
    for(int nb=0;nb<4;nb++){
      f32x4 s0 = (f32x4){0.f,0.f,0.f,0.f};
      f32x4 s1 = (f32x4){0.f,0.f,0.f,0.f};
      #pragma unroll
      for(int c=0;c<4;c++){
        bf16x8 kf = *(const bf16x8*)&Kc[(c*4+lg)*520 + (nb*16+l16)*8];
        s0 = __builtin_amdgcn_mfma_f32_16x16x32_bf16(qa[0][c], kf, s0, 0,0,0);
        s1 = __builtin_amdgcn_mfma_f32_16x16x32_bf16(qa[1][c], kf, s1, 0,0,0);
      }
      #pragma unroll
      for(int r=0;r<4;r++){
        Pw[(lg*4+r)*72 + nb*16 + l16]      = bfu(exp2f(s0[r]));
        Pw[(16+lg*4+r)*72 + nb*16 + l16]   = bfu(exp2f(s1[r]));
      }
    }
    #pragma unroll
    for(int ks=0;ks<2;ks++){
      bf16x8 pa0 = *(const bf16x8*)&Pw[l16*72 + ks*32 + lg*8];
      bf16x8 pa1 = *(const bf16x8*)&Pw[(16+l16)*72 + ks*32 + lg*8];
      lacc0 = __builtin_amdgcn_mfma_f32_16x16x32_bf16(pa0, ones, lacc0, 0,0,0);
      lacc1 = __builtin_amdgcn_mfma_f32_16x16x32_bf16(pa1, ones, lacc1, 0,0,0);
      #pragma unroll
      for(int n=0;n<8;n++){
        bf16x8 vf = *(const bf16x8*)&Vc[(ks*4+lg)*1032 + (n*16+l16)*8];
        acc[0][n] = __builtin_amdgcn_mfma_f32_16x16x32_bf16(pa0, vf, acc[0][n], 0,0,0);
        acc[1][n] = __builtin_amdgcn_mfma_f32_16x16x32_bf16(pa1, vf, acc[1][n], 0,0,0);
      }
    }
    __syncthreads();               // all waves done reading Kc/Vc
    if(more) STORE_STAGE();
    __syncthreads();               // staging visible
  }
#undef LOAD_STAGE
#undef STORE_STAGE
  // epilogue: O/l + residual -> h (f32)
  #pragma unroll
  for(int m=0;m<2;m++){
    #pragma unroll
    for(int r=0;r<4;r++){
      float lv = m ? lacc1[r] : lacc0[r];
      float inv = __builtin_amdgcn_rcpf(lv);
      int row = qt*128 + w*32 + m*16 + lg*4 + r;
      size_t base = ((size_t)(b*SS + row))*DIM + h*HD;
      #pragma unroll
      for(int n=0;n<8;n++){
        int d = n*16 + l16;
        out[base + d] = resid[base + d] + acc[m][n][r]*inv;
      }
    }
  }
}

// ---------------- fused FFN: 4 rows/block (r11-proven), split-K partials read inline -------
__global__ __launch_bounds__(256,1) void k_ffn(const float* __restrict__ part,
                                               const u16* __restrict__ wpk,
                                               const float* __restrict__ b1,
                                               const float* __restrict__ b3,
                                               float* __restrict__ racc){
  __shared__ float tl[4][32];
  __shared__ float red[4][64];
  const size_t PSTR = (size_t)NROWS*32;
  int tid = threadIdx.x;
  int row0 = blockIdx.x*4;
  if(tid<128){
    int rr = tid>>5, c = tid&31;
    size_t bx = (size_t)(row0+rr)*32 + c;
    tl[rr][c] = part[bx] + part[bx+PSTR] + part[bx+2*PSTR] + part[bx+3*PSTR];
  }
  __syncthreads();
  float acc[64];
  #pragma unroll
  for(int v=0;v<64;v++) acc[v]=0.f;
  for(int ii=0;ii<INNER/256;ii++){
    int j = tid + 256*ii;
    const u16* wr = wpk + (size_t)j*48;
    bf16x8 W1a = *(const bf16x8*)(wr);
    bf16x8 W1b = *(const bf16x8*)(wr+8);
    bf16x8 W3a = *(const bf16x8*)(wr+16);
    bf16x8 W3b = *(const bf16x8*)(wr+24);
    bf16x8 W2a = *(const bf16x8*)(wr+32);
    bf16x8 W2b = *(const bf16x8*)(wr+40);
    float bb1 = b1[j], bb3 = b3[j];
    #pragma unroll
    for(int rr=0;rr<4;rr++){
      float a1=0.f, a3=0.f;
      #pragma unroll
      for(int r=0;r<8;r++){
        a1 = fmaf(tl[rr][r],    (float)W1a[r], a1);
        a1 = fmaf(tl[rr][8+r],  (float)W1b[r], a1);
        a3 = fmaf(tl[rr][16+r], (float)W3a[r], a3);
        a3 = fmaf(tl[rr][24+r], (float)W3b[r], a3);
      }
      a1 = a1*0.0625f + bb1;
      a3 = a3*0.0625f + bb3;
      float u = a1*__builtin_amdgcn_rcpf(1.0f+exp2f(-a1*LOG2E)) * a3;
      #pragma unroll
      for(int c=0;c<8;c++){
        acc[rr*16+c]   = fmaf(u, (float)W2a[c], acc[rr*16+c]);
        acc[rr*16+8+c] = fmaf(u, (float)W2b[c], acc[rr*16+8+c]);
      }
    }
  }
  #pragma unroll
  for(int o=1;o<64;o<<=1){
    #pragma unroll
    for(int v=0;v<64;v++) acc[v] += __shfl_xor(acc[v], o);
  }
  int wv = tid>>6, lane = tid&63;
  if(lane==0){
    #pragma unroll
    for(int v=0;v<64;v++) red[wv][v] = acc[v];
  }
  __syncthreads();
  if(tid<64){
    float sum = red[0][tid]+red[1][tid]+red[2][tid]+red[3][tid];
    racc[(size_t)(row0 + (tid>>4))*16 + (tid&15)] = sum;
  }
}

// ---------------- final: out = h + racc @ w2_b /16 + b2 ----------------
__global__ __launch_bounds__(256) void k_out(const float* __restrict__ racc,
                                             const u16* __restrict__ w2P,
                                             const float* __restrict__ b2,
                                             float* __restrict__ io){
  __shared__ u16 wl[16*2048];
  int tid = threadIdx.x;
  #pragma unroll
  for(int ii=0;ii<16;ii++)
    ((uint4*)wl)[tid + 256*ii] = ((const uint4*)w2P)[tid + 256*ii];
  __syncthreads();
  int j0 = tid*8;
  float b2v[8];
  #pragma unroll
  for(int e=0;e<8;e++) b2v[e] = b2[j0+e];
  for(int rr=0;rr<8;rr++){
    int row = blockIdx.x*8 + rr;
    float rc[16];
    #pragma unroll
    for(int r=0;r<16;r++) rc[r] = racc[(size_t)row*16 + r];
    float pre[8];
    #pragma unroll
    for(int e=0;e<8;e++) pre[e]=0.f;
    #pragma unroll
    for(int r=0;r<16;r++){
      bf16x8 wv = *(const bf16x8*)&wl[r*2048 + j0];
      #pragma unroll
      for(int e=0;e<8;e++) pre[e] = fmaf(rc[r], (float)wv[e], pre[e]);
    }
    float* op = io + (size_t)row*DIM + j0;
    float4 h0 = ((const float4*)op)[0];
    float4 h1 = ((const float4*)op)[1];
    float4 o0, o1;
    o0.x = h0.x + pre[0]*0.0625f + b2v[0];
    o0.y = h0.y + pre[1]*0.0625f + b2v[1];
    o0.z = h0.z + pre[2]*0.0625f + b2v[2];
    o0.w = h0.w + pre[3]*0.0625f + b2v[3];
    o1.x = h1.x + pre[4]*0.0625f + b2v[4];
    o1.y = h1.y + pre[5]*0.0625f + b2v[5];
    o1.z = h1.z + pre[6]*0.0625f + b2v[6];
    o1.w = h1.w + pre[7]*0.0625f + b2v[7];
    ((float4*)op)[0] = o0;
    ((float4*)op)[1] = o1;
  }
}

extern "C" void kernel_launch(void* const* d_in, const int* in_sizes, int n_in,
                              void* d_out, int out_size, void* d_ws, size_t ws_size,
                              hipStream_t stream){
  const float* hidden = (const float*)d_in[0];
  // d_in[1] attention_mask: all-true, no-op in reference -> ignored
  const float* cosT = (const float*)d_in[2];
  const float* sinT = (const float*)d_in[3];
  const float* wq_a = (const float*)d_in[4];
  const float* wq_b = (const float*)d_in[5];
  const float* bq   = (const float*)d_in[6];
  const float* wk_a = (const float*)d_in[7];
  const float* wk_b = (const float*)d_in[8];
  const float* bk   = (const float*)d_in[9];
  const float* wv_a = (const float*)d_in[10];
  const float* wv_b = (const float*)d_in[11];
  const float* bv   = (const float*)d_in[12];
  const float* nqw  = (const float*)d_in[13];
  const float* nqb  = (const float*)d_in[14];
  const float* nkw  = (const float*)d_in[15];
  const float* nkb  = (const float*)d_in[16];
  const float* w1a  = (const float*)d_in[17];
  const float* w1b  = (const float*)d_in[18];
  const float* b1   = (const float*)d_in[19];
  const float* w3a  = (const float*)d_in[20];
  const float* w3b  = (const float*)d_in[21];
  const float* b3   = (const float*)d_in[22];
  const float* w2a  = (const float*)d_in[23];
  const float* w2b  = (const float*)d_in[24];
  const float* b2   = (const float*)d_in[25];
  const float* normw  = (const float*)d_in[26];
  const float* fnormw = (const float*)d_in[27];
  float* out = (float*)d_out;

  // ws layout (~53 MB); vtbuf aliases bufA (nh dead after loraAs, rms2 rewrites later)
  char* p = (char*)d_ws;
  u16* bufA = (u16*)p; p += (size_t)NROWS*DIM*2;       // nh -> (vtbuf) -> nf
  u16* qbuf = (u16*)p; p += (size_t)NROWS*DIM*2;       // q bf16 (exp2-scaled)
  u16* kbuf = (u16*)p; p += (size_t)NROWS*1024*2;
  u16* vbuf = (u16*)p; p += (size_t)NROWS*1024*2;
  float* racc = (float*)p; p += (size_t)NROWS*16*4;
  u16* wpk  = (u16*)p; p += (size_t)INNER*48*2;        // packed FFN weights bf16
  u16* wqP  = (u16*)p; p += (size_t)16*2048*2;
  u16* wkvP = (u16*)p; p += (size_t)2*16*1024*2;
  u16* w2P  = (u16*)p; p += (size_t)16*2048*2;
  float* part = (float*)p; p += (size_t)4*NROWS*48*4;  // split-K partials (3.1 MB)
  u16* vtbuf = bufA;                                    // [b*kvh][d][s] bf16

  k_prep<<<70,256,0,stream>>>(wq_b, wk_b, wv_b, w2b, w1b, w3b, w2a, wqP, wkvP, w2P, wpk);
  k_rms<<<NROWS,256,0,stream>>>(hidden, normw, bufA);                       // nh
  k_loraAs<3><<<768,256,0,stream>>>(bufA, wq_a, wk_a, wv_a, part);
  k_qb <<<NROWS/8,256,0,stream>>>(part, wqP, bq, nqw, nqb, cosT, sinT, qbuf);
  k_kvb<<<NROWS/8,256,0,stream>>>(part, wkvP, bk, nkw, nkb, bv, cosT, sinT, kbuf, vbuf);
  k_vt<<<1024,256,0,stream>>>(vbuf, vtbuf);
  k_attn<<<512,256,0,stream>>>(qbuf, kbuf, vtbuf, hidden, out);             // out = h
  k_rms<<<NROWS,256,0,stream>>>(out, fnormw, bufA);                         // nf
  k_loraAs<2><<<512,256,0,stream>>>(bufA, w1a, w3a, nullptr, part);
  k_ffn<<<NROWS/4,256,0,stream>>>(part, wpk, b1, b3, racc);
  k_out<<<NROWS/8,256,0,stream>>>(racc, w2P, b2, out);
}

// Round 15
// 338.181 us; speedup vs baseline: 1.0110x; 1.0110x over previous
//
#include <hip/hip_runtime.h>
#include <math.h>

typedef unsigned short u16;
typedef unsigned int u32;
typedef __bf16 bf16x8 __attribute__((ext_vector_type(8)));
typedef __bf16 bf16x4 __attribute__((ext_vector_type(4)));
typedef float f32x4 __attribute__((ext_vector_type(4)));

#define DIM 2048
#define NHEADS 16
#define NKVH 8
#define HD 128
#define RANK 16
#define INNER 5632
#define BB 2
#define SS 2048
#define NROWS (BB*SS)
#define EPS 1e-5f
#define QSC2 0.12751743560829201f   /* log2(e)/sqrt(128): exp2-domain softmax */
#define LOG2E 1.4426950408889634f

__device__ inline float bf2f(u16 u){ u32 x = ((u32)u)<<16; float f; __builtin_memcpy(&f,&x,4); return f; }
__device__ inline u16 f2bf(float f){ u32 u; __builtin_memcpy(&u,&f,4); u32 r = u + 0x7fffu + ((u>>16)&1u); return (u16)(r>>16); }
__device__ inline u32 pack2(float a, float b){ return (u32)f2bf(a) | ((u32)f2bf(b)<<16); }
__device__ inline u16 bfu(float f){ __bf16 b = (__bf16)f; u16 r; __builtin_memcpy(&r,&b,2); return r; }

__device__ inline float blockReduceSum(float v){
  __shared__ float r[4];
  #pragma unroll
  for(int o=1;o<64;o<<=1) v += __shfl_xor(v, o);
  int wv = threadIdx.x>>6;
  __syncthreads();
  if((threadIdx.x&63)==0) r[wv] = v;
  __syncthreads();
  return r[0]+r[1]+r[2]+r[3];
}

__device__ inline f32x4 blockReduceSum4(f32x4 v){
  __shared__ f32x4 r4[4];
  #pragma unroll
  for(int o=1;o<64;o<<=1){
    v.x += __shfl_xor(v.x,o); v.y += __shfl_xor(v.y,o);
    v.z += __shfl_xor(v.z,o); v.w += __shfl_xor(v.w,o);
  }
  int wv = threadIdx.x>>6;
  __syncthreads();
  if((threadIdx.x&63)==0) r4[wv]=v;
  __syncthreads();
  return r4[0]+r4[1]+r4[2]+r4[3];
}

// ---------------- one-time weight prep: castw (bid<48) + FFN pack (bid>=48) ----------------
__global__ __launch_bounds__(256) void k_prep(const float* __restrict__ wqb,
                                              const float* __restrict__ wkb,
                                              const float* __restrict__ wvb,
                                              const float* __restrict__ w2b,
                                              const float* __restrict__ w1b,
                                              const float* __restrict__ w3b,
                                              const float* __restrict__ w2a,
                                              u16* __restrict__ wqP,
                                              u16* __restrict__ wkvP,
                                              u16* __restrict__ w2P,
                                              u16* __restrict__ wpk){
  int bid = blockIdx.x;
  if(bid < 48){
    const float* src; u16* dst; int off;
    if(bid<16){ src=wqb; dst=wqP; off=bid; }
    else if(bid<24){ src=wkb; dst=wkvP; off=bid-16; }
    else if(bid<32){ src=wvb; dst=wkvP+16384; off=bid-24; }
    else { src=w2b; dst=w2P; off=bid-32; }
    int base = off*2048 + threadIdx.x*8;
    float4 a = ((const float4*)src)[base/4];
    float4 c = ((const float4*)src)[base/4+1];
    uint4 st;
    st.x = pack2(a.x,a.y); st.y = pack2(a.z,a.w);
    st.z = pack2(c.x,c.y); st.w = pack2(c.z,c.w);
    *(uint4*)&dst[base] = st;
  } else {
    int j = (bid-48)*256 + threadIdx.x;
    u32 pw[24];
    #pragma unroll
    for(int i=0;i<8;i++) pw[i]    = pack2(w1b[(size_t)(2*i)*INNER+j], w1b[(size_t)(2*i+1)*INNER+j]);
    #pragma unroll
    for(int i=0;i<8;i++) pw[8+i]  = pack2(w3b[(size_t)(2*i)*INNER+j], w3b[(size_t)(2*i+1)*INNER+j]);
    const float4* wp = (const float4*)(w2a + (size_t)j*16);
    #pragma unroll
    for(int q=0;q<4;q++){ float4 t=wp[q];
      pw[16+2*q] = pack2(t.x,t.y); pw[17+2*q] = pack2(t.z,t.w); }
    uint4* dst = (uint4*)(wpk + (size_t)j*48);
    #pragma unroll
    for(int i=0;i<6;i++) dst[i] = make_uint4(pw[4*i],pw[4*i+1],pw[4*i+2],pw[4*i+3]);
  }
}

// ---------------- RMSNorm: f32 in -> bf16 out (row = block) ----------------
__global__ __launch_bounds__(256) void k_rms(const float* __restrict__ x,
                                             const float* __restrict__ w,
                                             u16* __restrict__ out){
  size_t base = (size_t)blockIdx.x*DIM;
  int tid = threadIdx.x;
  float4 v0 = ((const float4*)(x+base))[tid*2];
  float4 v1 = ((const float4*)(x+base))[tid*2+1];
  float ss = v0.x*v0.x+v0.y*v0.y+v0.z*v0.z+v0.w*v0.w
           + v1.x*v1.x+v1.y*v1.y+v1.z*v1.z+v1.w*v1.w;
  ss = blockReduceSum(ss);
  float rstd = rsqrtf(ss*(1.0f/DIM) + EPS);
  float4 w0 = ((const float4*)w)[tid*2];
  float4 w1 = ((const float4*)w)[tid*2+1];
  uint4 st;
  st.x = pack2(v0.x*w0.x*rstd, v0.y*w0.y*rstd);
  st.y = pack2(v0.z*w0.z*rstd, v0.w*w0.w*rstd);
  st.z = pack2(v1.x*w1.x*rstd, v1.y*w1.y*rstd);
  st.w = pack2(v1.z*w1.z*rstd, v1.w*w1.w*rstd);
  *(uint4*)&out[base + tid*8] = st;
}

// ---------------- LoRA-A split-K: 4 rows/thread, K split in 4 chunks -> partials ------------
template<int NMAT>
__global__ __launch_bounds__(256) void k_loraAs(const u16* __restrict__ X,
                                                const float* __restrict__ A0,
                                                const float* __restrict__ A1,
                                                const float* __restrict__ A2,
                                                float* __restrict__ part){
  constexpr int LDO = NMAT*16;
  int bid = blockIdx.x;
  int mat = bid >> 8;
  int rem = bid & 255;
  int kc  = rem & 3;
  int blk = rem >> 2;
  const float* A = (mat==0) ? A0 : ((NMAT>2 && mat==2) ? A2 : A1);
  int tid = threadIdx.x;
  int ks = tid&15, rg = tid>>4;
  int row0 = blk*64 + rg*4;
  float acc[4][16];
  #pragma unroll
  for(int r=0;r<4;r++)
    #pragma unroll
    for(int c=0;c<16;c++) acc[r][c]=0.f;
  const u16* xp = X + (size_t)row0*DIM + kc*512 + ks*32;
  #pragma unroll
  for(int i8=0;i8<4;i8++){
    bf16x8 x0 = *(const bf16x8*)(xp + i8*8);
    bf16x8 x1 = *(const bf16x8*)(xp + DIM + i8*8);
    bf16x8 x2 = *(const bf16x8*)(xp + 2*DIM + i8*8);
    bf16x8 x3 = *(const bf16x8*)(xp + 3*DIM + i8*8);
    #pragma unroll
    for(int e=0;e<8;e++){
      int k = kc*512 + ks*32 + i8*8 + e;
      const float4* a = (const float4*)(A + (size_t)k*16);
      float4 a0=a[0], a1=a[1], a2=a[2], a3=a[3];
      float xs0=(float)x0[e], xs1=(float)x1[e], xs2=(float)x2[e], xs3=(float)x3[e];
      #define FMAROW(r, xs) \
        acc[r][0]=fmaf(xs,a0.x,acc[r][0]); acc[r][1]=fmaf(xs,a0.y,acc[r][1]); \
        acc[r][2]=fmaf(xs,a0.z,acc[r][2]); acc[r][3]=fmaf(xs,a0.w,acc[r][3]); \
        acc[r][4]=fmaf(xs,a1.x,acc[r][4]); acc[r][5]=fmaf(xs,a1.y,acc[r][5]); \
        acc[r][6]=fmaf(xs,a1.z,acc[r][6]); acc[r][7]=fmaf(xs,a1.w,acc[r][7]); \
        acc[r][8]=fmaf(xs,a2.x,acc[r][8]); acc[r][9]=fmaf(xs,a2.y,acc[r][9]); \
        acc[r][10]=fmaf(xs,a2.z,acc[r][10]); acc[r][11]=fmaf(xs,a2.w,acc[r][11]); \
        acc[r][12]=fmaf(xs,a3.x,acc[r][12]); acc[r][13]=fmaf(xs,a3.y,acc[r][13]); \
        acc[r][14]=fmaf(xs,a3.z,acc[r][14]); acc[r][15]=fmaf(xs,a3.w,acc[r][15]);
      FMAROW(0, xs0) FMAROW(1, xs1) FMAROW(2, xs2) FMAROW(3, xs3)
      #undef FMAROW
    }
  }
  #pragma unroll
  for(int o=1;o<16;o<<=1){
    #pragma unroll
    for(int r=0;r<4;r++)
      #pragma unroll
      for(int c=0;c<16;c++) acc[r][c] += __shfl_xor(acc[r][c], o);
  }
  if(ks==0){
    #pragma unroll
    for(int r=0;r<4;r++){
      float4* op = (float4*)(part + ((size_t)kc*NROWS + row0+r)*LDO + mat*16);
      op[0] = make_float4(acc[r][0],acc[r][1],acc[r][2],acc[r][3]);
      op[1] = make_float4(acc[r][4],acc[r][5],acc[r][6],acc[r][7]);
      op[2] = make_float4(acc[r][8],acc[r][9],acc[r][10],acc[r][11]);
      op[3] = make_float4(acc[r][12],acc[r][13],acc[r][14],acc[r][15]);
    }
  }
}

// ---------------- reduce 4 split-K partials (fixed order -> deterministic) ----------------
__global__ __launch_bounds__(256) void k_lred(const float* __restrict__ part,
                                              float* __restrict__ out, int n4){
  int i = blockIdx.x*256 + threadIdx.x;
  if(i >= n4) return;
  const float4* p = (const float4*)part;
  float4 a = p[i], b = p[i+n4], c = p[i+2*n4], d = p[i+3*n4];
  ((float4*)out)[i] = make_float4(a.x+b.x+c.x+d.x, a.y+b.y+c.y+d.y,
                                  a.z+b.z+c.z+d.z, a.w+b.w+c.w+d.w);
}

// ---------------- Q path: LoRA-B (bf16) + LayerNorm + RoPE + scale -> bf16 ----------------
__global__ __launch_bounds__(256) void k_qb(const float* __restrict__ xa,
                                            const u16* __restrict__ wqP,
                                            const float* __restrict__ bq,
                                            const float* __restrict__ nqw,
                                            const float* __restrict__ nqb,
                                            const float* __restrict__ cosT,
                                            const float* __restrict__ sinT,
                                            u16* __restrict__ qout){
  __shared__ u16 wl[16*2048];  // 64 KB bf16 weights
  int tid = threadIdx.x;
  #pragma unroll
  for(int ii=0;ii<16;ii++)
    ((uint4*)wl)[tid + 256*ii] = ((const uint4*)wqP)[tid + 256*ii];
  __syncthreads();
  int j0 = tid*8;
  float bqv[8], nwv[8], nbv[8];
  #pragma unroll
  for(int e=0;e<8;e++){ bqv[e]=bq[j0+e]; nwv[e]=nqw[j0+e]; nbv[e]=nqb[j0+e]; }
  int i0 = (j0&127)>>1;
  for(int rp=0;rp<4;rp++){
    int row = blockIdx.x*8 + rp*2;
    float pre[2][8];
    #pragma unroll
    for(int rr=0;rr<2;rr++){
      float xq[16];
      #pragma unroll
      for(int r=0;r<16;r++) xq[r] = xa[(size_t)(row+rr)*48 + r];
      #pragma unroll
      for(int e=0;e<8;e++) pre[rr][e]=0.f;
      #pragma unroll
      for(int r=0;r<16;r++){
        bf16x8 wv = *(const bf16x8*)&wl[r*2048 + j0];
        #pragma unroll
        for(int e=0;e<8;e++) pre[rr][e] = fmaf(xq[r], (float)wv[e], pre[rr][e]);
      }
      #pragma unroll
      for(int e=0;e<8;e++) pre[rr][e] = pre[rr][e]*0.0625f + bqv[e];
    }
    f32x4 sv = (f32x4){0.f,0.f,0.f,0.f};
    #pragma unroll
    for(int e=0;e<8;e++){
      sv.x += pre[0][e]; sv.y += pre[0][e]*pre[0][e];
      sv.z += pre[1][e]; sv.w += pre[1][e]*pre[1][e];
    }
    f32x4 red = blockReduceSum4(sv);
    #pragma unroll
    for(int rr=0;rr<2;rr++){
      float mu  = (rr?red.z:red.x)*(1.0f/DIM);
      float var = (rr?red.w:red.y)*(1.0f/DIM) - mu*mu;
      float rstd = rsqrtf(var + EPS);
      float qn[8];
      #pragma unroll
      for(int e=0;e<8;e++) qn[e] = (pre[rr][e]-mu)*rstd*nwv[e] + nbv[e];
      int spos = (row+rr) & (SS-1);
      const float* cp = cosT + spos*64;
      const float* sp = sinT + spos*64;
      uint4 st;
      u32 pk[4];
      #pragma unroll
      for(int p=0;p<4;p++){
        float c = cp[i0+p], sn = sp[i0+p];
        float x0 = qn[2*p], x1 = qn[2*p+1];
        pk[p] = pack2((x0*c - x1*sn)*QSC2, (x0*sn + x1*c)*QSC2);
      }
      st.x=pk[0]; st.y=pk[1]; st.z=pk[2]; st.w=pk[3];
      *(uint4*)&qout[(size_t)(row+rr)*2048 + j0] = st;
    }
  }
}

// ---------------- K/V path: LoRA-B (bf16) (+LN+RoPE for K) -> bf16 ----------------
__global__ __launch_bounds__(256) void k_kvb(const float* __restrict__ xa,
                                             const u16* __restrict__ wkvP,
                                             const float* __restrict__ bk,
                                             const float* __restrict__ nkw,
                                             const float* __restrict__ nkb,
                                             const float* __restrict__ bv,
                                             const float* __restrict__ cosT,
                                             const float* __restrict__ sinT,
                                             u16* __restrict__ kout,
                                             u16* __restrict__ vout){
  __shared__ u16 wl[2*16*1024];  // 64 KB: [0,16K)=wk_b, [16K,32K)=wv_b
  int tid = threadIdx.x;
  #pragma unroll
  for(int ii=0;ii<16;ii++)
    ((uint4*)wl)[tid + 256*ii] = ((const uint4*)wkvP)[tid + 256*ii];
  __syncthreads();
  int j0 = tid*4;
  float bkv[4], nwv[4], nbv[4], bvv[4];
  #pragma unroll
  for(int e=0;e<4;e++){ bkv[e]=bk[j0+e]; nwv[e]=nkw[j0+e]; nbv[e]=nkb[j0+e]; bvv[e]=bv[j0+e]; }
  int i0 = (j0&127)>>1;
  for(int rp=0;rp<4;rp++){
    int row = blockIdx.x*8 + rp*2;
    float pk_[2][4], pv_[2][4];
    #pragma unroll
    for(int rr=0;rr<2;rr++){
      float xk[16], xv[16];
      #pragma unroll
      for(int r=0;r<16;r++){ xk[r]=xa[(size_t)(row+rr)*48+16+r]; xv[r]=xa[(size_t)(row+rr)*48+32+r]; }
      #pragma unroll
      for(int e=0;e<4;e++){ pk_[rr][e]=0.f; pv_[rr][e]=0.f; }
      #pragma unroll
      for(int r=0;r<16;r++){
        bf16x4 wk4 = *(const bf16x4*)&wl[r*1024 + j0];
        bf16x4 wv4 = *(const bf16x4*)&wl[16384 + r*1024 + j0];
        #pragma unroll
        for(int e=0;e<4;e++){ pk_[rr][e]=fmaf(xk[r],(float)wk4[e],pk_[rr][e]); pv_[rr][e]=fmaf(xv[r],(float)wv4[e],pv_[rr][e]); }
      }
      #pragma unroll
      for(int e=0;e<4;e++){ pk_[rr][e]=pk_[rr][e]*0.0625f + bkv[e]; pv_[rr][e]=pv_[rr][e]*0.0625f + bvv[e]; }
    }
    f32x4 sv = (f32x4){0.f,0.f,0.f,0.f};
    #pragma unroll
    for(int e=0;e<4;e++){
      sv.x += pk_[0][e]; sv.y += pk_[0][e]*pk_[0][e];
      sv.z += pk_[1][e]; sv.w += pk_[1][e]*pk_[1][e];
    }
    f32x4 red = blockReduceSum4(sv);
    #pragma unroll
    for(int rr=0;rr<2;rr++){
      float mu  = (rr?red.z:red.x)*(1.0f/1024.0f);
      float var = (rr?red.w:red.y)*(1.0f/1024.0f) - mu*mu;
      float rstd = rsqrtf(var + EPS);
      float kn[4];
      #pragma unroll
      for(int e=0;e<4;e++) kn[e] = (pk_[rr][e]-mu)*rstd*nwv[e] + nbv[e];
      int spos = (row+rr) & (SS-1);
      const float* cp = cosT + spos*64;
      const float* sp = sinT + spos*64;
      uint2 stk;
      { float c=cp[i0],   sn=sp[i0];   stk.x = pack2(kn[0]*c - kn[1]*sn, kn[0]*sn + kn[1]*c); }
      { float c=cp[i0+1], sn=sp[i0+1]; stk.y = pack2(kn[2]*c - kn[3]*sn, kn[2]*sn + kn[3]*c); }
      *(uint2*)&kout[(size_t)(row+rr)*1024 + j0] = stk;
      uint2 stv; stv.x = pack2(pv_[rr][0],pv_[rr][1]); stv.y = pack2(pv_[rr][2],pv_[rr][3]);
      *(uint2*)&vout[(size_t)(row+rr)*1024 + j0] = stv;
    }
  }
}

// ---------------- V transpose: [b][s][kvh][d] -> [b*kvh][d][s] (64x64 tiles) ----------------
__global__ __launch_bounds__(256) void k_vt(const u16* __restrict__ v,
                                            u16* __restrict__ vt){
  __shared__ u16 tl[64*68];
  int bid = blockIdx.x;
  int st = bid & 31;
  int dt = (bid>>5) & 1;
  int bh = bid>>6;          // b*8 + kvh
  int b = bh>>3, kvh = bh&7;
  int tid = threadIdx.x;
  int s0 = st*64, d0 = dt*64;
  {
    int s_l = tid>>2, dg = tid&3;
    const u16* src = v + ((size_t)(b*SS + s0 + s_l)*NKVH + kvh)*HD + d0 + dg*16;
    *(uint4*)&tl[s_l*68 + dg*16]     = *(const uint4*)(src);
    *(uint4*)&tl[s_l*68 + dg*16 + 8] = *(const uint4*)(src + 8);
  }
  __syncthreads();
  {
    int d_l = tid>>2, sg = tid&3;
    u32 pk[8];
    #pragma unroll
    for(int i=0;i<8;i++){
      u16 a = tl[(sg*16 + 2*i)*68 + d_l];
      u16 c = tl[(sg*16 + 2*i+1)*68 + d_l];
      pk[i] = (u32)a | ((u32)c<<16);
    }
    u16* dst = vt + ((size_t)bh*HD + d0 + d_l)*SS + s0 + sg*16;
    ((uint4*)dst)[0] = make_uint4(pk[0],pk[1],pk[2],pk[3]);
    ((uint4*)dst)[1] = make_uint4(pk[4],pk[5],pk[6],pk[7]);
  }
}

// ---------------- Flash attention (16x16 MFMA, 2 m-blocks/wave, static softmax) ------------
// grid 512; block 256 = 4 waves x 32 q-rows. Named-register staging (no lambdas/arrays).
__global__ __launch_bounds__(256,2) void k_attn(const u16* __restrict__ qb,
                                                const u16* __restrict__ kb,
                                                const u16* __restrict__ vt,
                                                const float* __restrict__ resid,
                                                float* __restrict__ out){
  __shared__ u16 Kc[16*520];    // 16640 B
  __shared__ u16 Vc[8*1032];    // 16512 B
  __shared__ u16 Pl[4][32*72];  // 18432 B
  int bid = ((int)blockIdx.x & 7)*64 + ((int)blockIdx.x >> 3);  // XCD swizzle (512%8==0)
  int qt = bid & 15;
  int h  = (bid>>4) & 15;
  int b  = bid>>8;
  int kvh = h>>1;
  int tid = threadIdx.x;
  int w = tid>>6, lane = tid&63;
  int l16 = lane&15, lg = lane>>4;

  bf16x8 qa[2][4];
  #pragma unroll
  for(int m=0;m<2;m++){
    const u16* qp = qb + ((size_t)(b*SS + qt*128 + w*32 + m*16 + l16))*DIM + h*HD + lg*8;
    #pragma unroll
    for(int c=0;c<4;c++) qa[m][c] = *(const bf16x8*)(qp + c*32);
  }
  f32x4 acc[2][8];
  #pragma unroll
  for(int m=0;m<2;m++)
    #pragma unroll
    for(int n=0;n<8;n++) acc[m][n] = (f32x4){0.f,0.f,0.f,0.f};
  f32x4 lacc0 = (f32x4){0.f,0.f,0.f,0.f};
  f32x4 lacc1 = (f32x4){0.f,0.f,0.f,0.f};
  bf16x8 ones;
  #pragma unroll
  for(int e=0;e<8;e++) ones[e] = (__bf16)1.0f;

  u16* Pw = Pl[w];
  const u16* vtb = vt + (size_t)(b*NKVH + kvh)*HD*SS;
  const u16* kbb = kb + ((size_t)(b*SS)*NKVH + kvh)*HD;
  int k_key = tid>>4, k_dg = tid&15;
  int v_d   = tid>>3, v_kc = tid&7;
  uint4 kA,kB,kC,kD,vA,vB,vC,vD;       // named staging regs (no arrays!)

#define LOAD_STAGE(KT) do{ \
    const u16* ksrc_ = kbb + (size_t)(KT)*64*1024; \
    const u16* vsrc_ = vtb + (KT)*64; \
    kA = *(const uint4*)(ksrc_ + (size_t)(k_key     )*1024 + k_dg*8); \
    kB = *(const uint4*)(ksrc_ + (size_t)(k_key + 16)*1024 + k_dg*8); \
    kC = *(const uint4*)(ksrc_ + (size_t)(k_key + 32)*1024 + k_dg*8); \
    kD = *(const uint4*)(ksrc_ + (size_t)(k_key + 48)*1024 + k_dg*8); \
    vA = *(const uint4*)(vsrc_ + (size_t)(v_d      )*SS + v_kc*8); \
    vB = *(const uint4*)(vsrc_ + (size_t)(v_d + 32 )*SS + v_kc*8); \
    vC = *(const uint4*)(vsrc_ + (size_t)(v_d + 64 )*SS + v_kc*8); \
    vD = *(const uint4*)(vsrc_ + (size_t)(v_d + 96 )*SS + v_kc*8); \
  }while(0)
#define STORE_STAGE() do{ \
    *(uint4*)&Kc[k_dg*520 + (k_key     )*8] = kA; \
    *(uint4*)&Kc[k_dg*520 + (k_key + 16)*8] = kB; \
    *(uint4*)&Kc[k_dg*520 + (k_key + 32)*8] = kC; \
    *(uint4*)&Kc[k_dg*520 + (k_key + 48)*8] = kD; \
    *(uint4*)&Vc[v_kc*1032 + (v_d      )*8] = vA; \
    *(uint4*)&Vc[v_kc*1032 + (v_d + 32 )*8] = vB; \
    *(uint4*)&Vc[v_kc*1032 + (v_d + 64 )*8] = vC; \
    *(uint4*)&Vc[v_kc*1032 + (v_d + 96 )*8] = vD; \
  }while(0)

  LOAD_STAGE(0);
  STORE_STAGE();
  __syncthreads();

  for(int kt=0; kt<SS/64; kt++){
    bool more = (kt+1) < SS/64;
    if(more) LOAD_STAGE(kt+1);    // in flight during compute (T14)
    #pragma unroll
    for(int nb=0;nb<4;nb++){
      f32x4 s0 = (f32x4){0.f,0.f,0.f,0.f};
      f32x4 s1 = (f32x4){0.f,0.f,0.f,0.f};
      #pragma unroll
      for(int c=0;c<4;c++){
        bf16x8 kf = *(const bf16x8*)&Kc[(c*4+lg)*520 + (nb*16+l16)*8];
        s0 = __builtin_amdgcn_mfma_f32_16x16x32_bf16(qa[0][c], kf, s0, 0,0,0);
        s1 = __builtin_amdgcn_mfma_f32_16x16x32_bf16(qa[1][c], kf, s1, 0,0,0);
      }
      #pragma unroll
      for(int r=0;r<4;r++){
        Pw[(lg*4+r)*72 + nb*16 + l16]      = bfu(exp2f(s0[r]));
        Pw[(16+lg*4+r)*72 + nb*16 + l16]   = bfu(exp2f(s1[r]));
      }
    }
    #pragma unroll
    for(int ks=0;ks<2;ks++){
      bf16x8 pa0 = *(const bf16x8*)&Pw[l16*72 + ks*32 + lg*8];
      bf16x8 pa1 = *(const bf16x8*)&Pw[(16+l16)*72 + ks*32 + lg*8];
      lacc0 = __builtin_amdgcn_mfma_f32_16x16x32_bf16(pa0, ones, lacc0, 0,0,0);
      lacc1 = __builtin_amdgcn_mfma_f32_16x16x32_bf16(pa1, ones, lacc1, 0,0,0);
      #pragma unroll
      for(int n=0;n<8;n++){
        bf16x8 vf = *(const bf16x8*)&Vc[(ks*4+lg)*1032 + (n*16+l16)*8];
        acc[0][n] = __builtin_amdgcn_mfma_f32_16x16x32_bf16(pa0, vf, acc[0][n], 0,0,0);
        acc[1][n] = __builtin_amdgcn_mfma_f32_16x16x32_bf16(pa1, vf, acc[1][n], 0,0,0);
      }
    }
    __syncthreads();               // all waves done reading Kc/Vc
    if(more) STORE_STAGE();
    __syncthreads();               // staging visible
  }
#undef LOAD_STAGE
#undef STORE_STAGE
  // epilogue: O/l + residual -> h (f32)
  #pragma unroll
  for(int m=0;m<2;m++){
    #pragma unroll
    for(int r=0;r<4;r++){
      float lv = m ? lacc1[r] : lacc0[r];
      float inv = __builtin_amdgcn_rcpf(lv);
      int row = qt*128 + w*32 + m*16 + lg*4 + r;
      size_t base = ((size_t)(b*SS + row))*DIM + h*HD;
      #pragma unroll
      for(int n=0;n<8;n++){
        int d = n*16 + l16;
        out[base + d] = resid[base + d] + acc[m][n][r]*inv;
      }
    }
  }
}

// ---------------- fused FFN: 4 rows/block (r11-proven), split-K partials read inline -------
__global__ __launch_bounds__(256,1) void k_ffn(const float* __restrict__ part,
                                               const u16* __restrict__ wpk,
                                               const float* __restrict__ b1,
                                               const float* __restrict__ b3,
                                               float* __restrict__ racc){
  __shared__ float tl[4][32];
  __shared__ float red[4][64];
  const size_t PSTR = (size_t)NROWS*32;
  int tid = threadIdx.x;
  int row0 = blockIdx.x*4;
  if(tid<128){
    int rr = tid>>5, c = tid&31;
    size_t bx = (size_t)(row0+rr)*32 + c;
    tl[rr][c] = part[bx] + part[bx+PSTR] + part[bx+2*PSTR] + part[bx+3*PSTR];
  }
  __syncthreads();
  float acc[64];
  #pragma unroll
  for(int v=0;v<64;v++) acc[v]=0.f;
  for(int ii=0;ii<INNER/256;ii++){
    int j = tid + 256*ii;
    const u16* wr = wpk + (size_t)j*48;
    bf16x8 W1a = *(const bf16x8*)(wr);
    bf16x8 W1b = *(const bf16x8*)(wr+8);
    bf16x8 W3a = *(const bf16x8*)(wr+16);
    bf16x8 W3b = *(const bf16x8*)(wr+24);
    bf16x8 W2a = *(const bf16x8*)(wr+32);
    bf16x8 W2b = *(const bf16x8*)(wr+40);
    float bb1 = b1[j], bb3 = b3[j];
    #pragma unroll
    for(int rr=0;rr<4;rr++){
      float a1=0.f, a3=0.f;
      #pragma unroll
      for(int r=0;r<8;r++){
        a1 = fmaf(tl[rr][r],    (float)W1a[r], a1);
        a1 = fmaf(tl[rr][8+r],  (float)W1b[r], a1);
        a3 = fmaf(tl[rr][16+r], (float)W3a[r], a3);
        a3 = fmaf(tl[rr][24+r], (float)W3b[r], a3);
      }
      a1 = a1*0.0625f + bb1;
      a3 = a3*0.0625f + bb3;
      float u = a1*__builtin_amdgcn_rcpf(1.0f+exp2f(-a1*LOG2E)) * a3;
      #pragma unroll
      for(int c=0;c<8;c++){
        acc[rr*16+c]   = fmaf(u, (float)W2a[c], acc[rr*16+c]);
        acc[rr*16+8+c] = fmaf(u, (float)W2b[c], acc[rr*16+8+c]);
      }
    }
  }
  #pragma unroll
  for(int o=1;o<64;o<<=1){
    #pragma unroll
    for(int v=0;v<64;v++) acc[v] += __shfl_xor(acc[v], o);
  }
  int wv = tid>>6, lane = tid&63;
  if(lane==0){
    #pragma unroll
    for(int v=0;v<64;v++) red[wv][v] = acc[v];
  }
  __syncthreads();
  if(tid<64){
    float sum = red[0][tid]+red[1][tid]+red[2][tid]+red[3][tid];
    racc[(size_t)(row0 + (tid>>4))*16 + (tid&15)] = sum;
  }
}

// ---------------- final: out = h + racc @ w2_b /16 + b2 ----------------
__global__ __launch_bounds__(256) void k_out(const float* __restrict__ racc,
                                             const u16* __restrict__ w2P,
                                             const float* __restrict__ b2,
                                             float* __restrict__ io){
  __shared__ u16 wl[16*2048];
  int tid = threadIdx.x;
  #pragma unroll
  for(int ii=0;ii<16;ii++)
    ((uint4*)wl)[tid + 256*ii] = ((const uint4*)w2P)[tid + 256*ii];
  __syncthreads();
  int j0 = tid*8;
  float b2v[8];
  #pragma unroll
  for(int e=0;e<8;e++) b2v[e] = b2[j0+e];
  for(int rr=0;rr<8;rr++){
    int row = blockIdx.x*8 + rr;
    float rc[16];
    #pragma unroll
    for(int r=0;r<16;r++) rc[r] = racc[(size_t)row*16 + r];
    float pre[8];
    #pragma unroll
    for(int e=0;e<8;e++) pre[e]=0.f;
    #pragma unroll
    for(int r=0;r<16;r++){
      bf16x8 wv = *(const bf16x8*)&wl[r*2048 + j0];
      #pragma unroll
      for(int e=0;e<8;e++) pre[e] = fmaf(rc[r], (float)wv[e], pre[e]);
    }
    float* op = io + (size_t)row*DIM + j0;
    float4 h0 = ((const float4*)op)[0];
    float4 h1 = ((const float4*)op)[1];
    float4 o0, o1;
    o0.x = h0.x + pre[0]*0.0625f + b2v[0];
    o0.y = h0.y + pre[1]*0.0625f + b2v[1];
    o0.z = h0.z + pre[2]*0.0625f + b2v[2];
    o0.w = h0.w + pre[3]*0.0625f + b2v[3];
    o1.x = h1.x + pre[4]*0.0625f + b2v[4];
    o1.y = h1.y + pre[5]*0.0625f + b2v[5];
    o1.z = h1.z + pre[6]*0.0625f + b2v[6];
    o1.w = h1.w + pre[7]*0.0625f + b2v[7];
    ((float4*)op)[0] = o0;
    ((float4*)op)[1] = o1;
  }
}

extern "C" void kernel_launch(void* const* d_in, const int* in_sizes, int n_in,
                              void* d_out, int out_size, void* d_ws, size_t ws_size,
                              hipStream_t stream){
  const float* hidden = (const float*)d_in[0];
  // d_in[1] attention_mask: all-true, no-op in reference -> ignored
  const float* cosT = (const float*)d_in[2];
  const float* sinT = (const float*)d_in[3];
  const float* wq_a = (const float*)d_in[4];
  const float* wq_b = (const float*)d_in[5];
  const float* bq   = (const float*)d_in[6];
  const float* wk_a = (const float*)d_in[7];
  const float* wk_b = (const float*)d_in[8];
  const float* bk   = (const float*)d_in[9];
  const float* wv_a = (const float*)d_in[10];
  const float* wv_b = (const float*)d_in[11];
  const float* bv   = (const float*)d_in[12];
  const float* nqw  = (const float*)d_in[13];
  const float* nqb  = (const float*)d_in[14];
  const float* nkw  = (const float*)d_in[15];
  const float* nkb  = (const float*)d_in[16];
  const float* w1a  = (const float*)d_in[17];
  const float* w1b  = (const float*)d_in[18];
  const float* b1   = (const float*)d_in[19];
  const float* w3a  = (const float*)d_in[20];
  const float* w3b  = (const float*)d_in[21];
  const float* b3   = (const float*)d_in[22];
  const float* w2a  = (const float*)d_in[23];
  const float* w2b  = (const float*)d_in[24];
  const float* b2   = (const float*)d_in[25];
  const float* normw  = (const float*)d_in[26];
  const float* fnormw = (const float*)d_in[27];
  float* out = (float*)d_out;

  // ws layout (~56 MB); vtbuf aliases bufA (nh dead after loraAs, rms2 rewrites later)
  char* p = (char*)d_ws;
  u16* bufA = (u16*)p; p += (size_t)NROWS*DIM*2;       // nh -> (vtbuf) -> nf
  u16* qbuf = (u16*)p; p += (size_t)NROWS*DIM*2;       // q bf16 (exp2-scaled)
  u16* kbuf = (u16*)p; p += (size_t)NROWS*1024*2;
  u16* vbuf = (u16*)p; p += (size_t)NROWS*1024*2;
  float* xa   = (float*)p; p += (size_t)NROWS*48*4;
  float* racc = (float*)p; p += (size_t)NROWS*16*4;
  u16* wpk  = (u16*)p; p += (size_t)INNER*48*2;        // packed FFN weights bf16
  u16* wqP  = (u16*)p; p += (size_t)16*2048*2;
  u16* wkvP = (u16*)p; p += (size_t)2*16*1024*2;
  u16* w2P  = (u16*)p; p += (size_t)16*2048*2;
  float* part = (float*)p; p += (size_t)4*NROWS*48*4;  // split-K partials (3.1 MB)
  u16* vtbuf = bufA;                                    // [b*kvh][d][s] bf16

  k_prep<<<70,256,0,stream>>>(wq_b, wk_b, wv_b, w2b, w1b, w3b, w2a, wqP, wkvP, w2P, wpk);
  k_rms<<<NROWS,256,0,stream>>>(hidden, normw, bufA);                       // nh
  k_loraAs<3><<<768,256,0,stream>>>(bufA, wq_a, wk_a, wv_a, part);
  k_lred<<<192,256,0,stream>>>(part, xa, NROWS*48/4);
  k_qb <<<NROWS/8,256,0,stream>>>(xa, wqP, bq, nqw, nqb, cosT, sinT, qbuf);
  k_kvb<<<NROWS/8,256,0,stream>>>(xa, wkvP, bk, nkw, nkb, bv, cosT, sinT, kbuf, vbuf);
  k_vt<<<1024,256,0,stream>>>(vbuf, vtbuf);
  k_attn<<<512,256,0,stream>>>(qbuf, kbuf, vtbuf, hidden, out);             // out = h
  k_rms<<<NROWS,256,0,stream>>>(out, fnormw, bufA);                         // nf
  k_loraAs<2><<<512,256,0,stream>>>(bufA, w1a, w3a, nullptr, part);
  k_ffn<<<NROWS/4,256,0,stream>>>(part, wpk, b1, b3, racc);
  k_out<<<NROWS/8,256,0,stream>>>(racc, w2P, b2, out);
}